// Round 21
// baseline (113.453 us; speedup 1.0000x reference)
//
#include <hip/hip_runtime.h>
#include <hip/hip_bf16.h>

typedef __attribute__((ext_vector_type(8))) short short8;
typedef __attribute__((ext_vector_type(4))) short short4v;
typedef __attribute__((ext_vector_type(4))) float f32x4;

#define TT 4096
#define DM 1024
#define NH 16
#define NPROJ 1280   // 128 qs + 128 ks + 256 qg + 256 kg + 512 v
#define DATTN 512

static __device__ __forceinline__ short f2bf(float f) {
  __hip_bfloat16 h = __float2bfloat16(f);
  return *reinterpret_cast<short*>(&h);
}
static __device__ __forceinline__ unsigned pk2(float a, float b) {
  float2 t; t.x = a; t.y = b;
  __hip_bfloat162 r = __float22bfloat162_rn(t);
  return *reinterpret_cast<unsigned*>(&r);
}

// ---------------- fused prep: x->bf16, ow->bf16, wcat concat (one launch) ----------------
#define NB_X   (TT * DM / 4 / 256)        // 4096 blocks
#define NB_OW  (DM * DATTN / 4 / 256)     // 512 blocks
#define NB_WC  (NPROJ * DM / 4 / 256)     // 1280 blocks
__global__ __launch_bounds__(256) void k_prep(const float* __restrict__ x,
    const float* __restrict__ ow, const float* __restrict__ qs, const float* __restrict__ ks,
    const float* __restrict__ qg, const float* __restrict__ kg, const float* __restrict__ vw,
    __hip_bfloat16* __restrict__ Xbf, __hip_bfloat16* __restrict__ OW,
    __hip_bfloat16* __restrict__ Wcat) {
  const int b = blockIdx.x;
  if (b < NB_X) {
    const int i = b * 256 + threadIdx.x;
    float4 v = reinterpret_cast<const float4*>(x)[i];
    short4v o;
    o[0] = f2bf(v.x); o[1] = f2bf(v.y); o[2] = f2bf(v.z); o[3] = f2bf(v.w);
    reinterpret_cast<short4v*>(Xbf)[i] = o;
  } else if (b < NB_X + NB_OW) {
    const int i = (b - NB_X) * 256 + threadIdx.x;
    float4 v = reinterpret_cast<const float4*>(ow)[i];
    short4v o;
    o[0] = f2bf(v.x); o[1] = f2bf(v.y); o[2] = f2bf(v.z); o[3] = f2bf(v.w);
    reinterpret_cast<short4v*>(OW)[i] = o;
  } else {
    const int i = (b - NB_X - NB_OW) * 256 + threadIdx.x;
    const int idx = i * 4;
    const int row = idx >> 10;
    const int col = idx & 1023;
    const float* src;
    if (row < 128)      src = qs + (size_t)row * DM;
    else if (row < 256) src = ks + (size_t)(row - 128) * DM;
    else if (row < 512) src = qg + (size_t)(row - 256) * DM;
    else if (row < 768) src = kg + (size_t)(row - 512) * DM;
    else                src = vw + (size_t)(row - 768) * DM;
    float4 v = *reinterpret_cast<const float4*>(src + col);
    short4v o;
    o[0] = f2bf(v.x); o[1] = f2bf(v.y); o[2] = f2bf(v.z); o[3] = f2bf(v.w);
    *reinterpret_cast<short4v*>(Wcat + idx) = o;
  }
}

// ---------------- bf16 GEMM, B^T layout, BM=64 BN=128 BK=64, double-buffered ----------
// EPI=0: plain fp32 C write (out projection).
// EPI=1: fused RoPE/pack epilogue (proj GEMM), blockIdx.y selects region.
template<int EPI>
__global__ __launch_bounds__(256) void k_gemm_bt(const __hip_bfloat16* __restrict__ A,
    const __hip_bfloat16* __restrict__ B, void* __restrict__ Cv, int M, int N, int K,
    __hip_bfloat16* __restrict__ Qp, __hip_bfloat16* __restrict__ Kp,
    __hip_bfloat16* __restrict__ Vt, const float* __restrict__ ls,
    const int* __restrict__ posp) {
  __shared__ alignas(16) __hip_bfloat16 lA[2][2][64 * 32];    // [buf][kk]
  __shared__ alignas(16) __hip_bfloat16 lB[2][2][128 * 32];   // [buf][kk]
  const int tid = threadIdx.x;
  const int lane = tid & 63;
  const int wid = tid >> 6;
  const int m0 = blockIdx.x * 64, n0 = blockIdx.y * 128;
  const int wm = (wid >> 1) * 32, wn = (wid & 1) * 64;
  const int srow = tid >> 2;          // 0..63
  const int scol = (tid & 3) * 8;     // bf16 elements within a 32-col panel
  const int fr = lane & 15, fk = (lane >> 4) * 8;
  f32x4 acc[2][4];
  const f32x4 zz = {0.f, 0.f, 0.f, 0.f};
#pragma unroll
  for (int m = 0; m < 2; ++m)
#pragma unroll
    for (int n = 0; n < 4; ++n) acc[m][n] = zz;

  auto stage = [&](int kt, int buf) {
#pragma unroll
    for (int kk = 0; kk < 2; ++kk) {
      const int kcol = kt + kk * 32 + scol;
      const __hip_bfloat16* ga0 = A + (size_t)(m0 + srow) * K + kcol;
      const __hip_bfloat16* gb0 = B + (size_t)(n0 + srow) * K + kcol;
      const __hip_bfloat16* gb1 = B + (size_t)(n0 + 64 + srow) * K + kcol;
      __builtin_amdgcn_global_load_lds((const __attribute__((address_space(1))) void*)ga0,
          (__attribute__((address_space(3))) void*)(lA[buf][kk] + srow * 32 + scol), 16, 0, 0);
      __builtin_amdgcn_global_load_lds((const __attribute__((address_space(1))) void*)gb0,
          (__attribute__((address_space(3))) void*)(lB[buf][kk] + srow * 32 + scol), 16, 0, 0);
      __builtin_amdgcn_global_load_lds((const __attribute__((address_space(1))) void*)gb1,
          (__attribute__((address_space(3))) void*)(lB[buf][kk] + (64 + srow) * 32 + scol), 16, 0, 0);
    }
  };
  stage(0, 0);
  int buf = 0;
  for (int kt = 0; kt < K; kt += 64) {
    __syncthreads();   // staging of buf complete; prev reads of buf^1 done
    if (kt + 64 < K) stage(kt + 64, buf ^ 1);
#pragma unroll
    for (int kk = 0; kk < 2; ++kk) {
      short8 af[2], bfr[4];
#pragma unroll
      for (int m = 0; m < 2; ++m)
        af[m] = *reinterpret_cast<const short8*>(lA[buf][kk] + (wm + m * 16 + fr) * 32 + fk);
#pragma unroll
      for (int n = 0; n < 4; ++n)
        bfr[n] = *reinterpret_cast<const short8*>(lB[buf][kk] + (wn + n * 16 + fr) * 32 + fk);
#pragma unroll
      for (int m = 0; m < 2; ++m)
#pragma unroll
        for (int n = 0; n < 4; ++n)
          acc[m][n] = __builtin_amdgcn_mfma_f32_16x16x32_bf16(af[m], bfr[n], acc[m][n], 0, 0, 0);
    }
    buf ^= 1;
  }
  const int cr = (lane >> 4) * 4, cc = lane & 15;
  if (EPI == 0) {
#pragma unroll
    for (int m = 0; m < 2; ++m)
#pragma unroll
      for (int n = 0; n < 4; ++n)
#pragma unroll
        for (int j = 0; j < 4; ++j) {
          const int row = m0 + wm + m * 16 + cr + j;
          const int col = n0 + wn + n * 16 + cc;
          ((float*)Cv)[(size_t)row * N + col] = acc[m][n][j];
        }
    return;
  }
  // ---- EPI=1: fused RoPE/pack epilogue ----
  const int y = blockIdx.y;
  const float QSC = 0.20412414523193154f * 1.4426950408889634f;  // 1/sqrt(24)*log2(e)
  if (y < 2) {
    __hip_bfloat16* P = (y == 0) ? Qp : Kp;
    const __hip_bfloat16 zb = __float2bfloat16(0.f);
#pragma unroll
    for (int n = 0; n < 4; ++n) {
      const int cl = wn + n * 16 + cc;        // 0..127
      const int h = cl >> 3, d = cl & 7;
      const float sc = (y == 0) ? QSC * __expf(ls[h]) : 1.0f;
#pragma unroll
      for (int m = 0; m < 2; ++m)
#pragma unroll
        for (int j = 0; j < 4; ++j) {
          const int row = m0 + wm + m * 16 + cr + j;
          __hip_bfloat16* base = P + ((size_t)h * TT + row) * 32;
          base[d] = __float2bfloat16(acc[m][n][j] * sc);
          base[24 + d] = zb;
        }
    }
  } else if (y < 6) {
    const int isQ = (y < 4);
    __hip_bfloat16* P = isQ ? Qp : Kp;
    const int segbase = isQ ? 256 : 512;
    const float invf[8] = {1.0f, 0.31622776601683794f, 0.1f, 0.031622776601683794f,
                           0.01f, 0.0031622776601683794f, 0.001f, 0.00031622776601683794f};
    const float fr_ = invf[cc & 7];
    const float pofs = (float)posp[0];
    const int lo = (cc < 8);
    const int d = 8 + cc;                     // 8..24
#pragma unroll
    for (int n = 0; n < 4; ++n) {
      const int h = (y * 128 + wn + n * 16 - segbase) >> 4;
      const float sc = isQ ? QSC * __expf(ls[h]) : 1.0f;
#pragma unroll
      for (int m = 0; m < 2; ++m)
#pragma unroll
        for (int j = 0; j < 4; ++j) {
          const int row = m0 + wm + m * 16 + cr + j;
          const float own = acc[m][n][j];
          const float oth = __shfl_xor(own, 8, 64);
          float ss, cs;
          __sincosf((row + pofs) * fr_, &ss, &cs);
          const float out = lo ? (own * cs - oth * ss) : (oth * ss + own * cs);
          P[((size_t)h * TT + row) * 32 + d] = __float2bfloat16(out * sc);
        }
    }
  } else {
#pragma unroll
    for (int n = 0; n < 4; ++n) {
      const int local = y * 128 + wn + n * 16 - 768 + cc;   // 0..511
      const int h = local >> 5, d = local & 31;
#pragma unroll
      for (int m = 0; m < 2; ++m) {
        short4v pk;
#pragma unroll
        for (int j = 0; j < 4; ++j) pk[j] = f2bf(acc[m][n][j]);
        const int row0 = m0 + wm + m * 16 + cr;   // multiple of 4
        *reinterpret_cast<short4v*>(Vt + ((size_t)h * 32 + d) * TT + row0) = pk;
      }
    }
  }
}

// ---------------- causal flash attention: KVBLK=128 staging + in-register pi-PV -------
// 1024 blocks x 4 waves; block = (head, 64-row q-block), LPT (qb descending).
// 2x16KB LDS buffers (K 8KB + V 8KB per 128-kv tile) -> still 4 blocks/CU.
// Barrier rounds halved (ceil(nt/2)); 2 inner 64-kv steps per barrier.
// P never touches LDS (pi permutation, verified R13): PV B-frag = lane's own
// packed s values; V^T read pi-permuted as 2x b64 per operand.
// LDS layouts = exact read order; staging inverse-permutes the global source.
__global__ __launch_bounds__(256) void k_attn(const __hip_bfloat16* __restrict__ Qp,
    const __hip_bfloat16* __restrict__ Kp, const __hip_bfloat16* __restrict__ Vt,
    __hip_bfloat16* __restrict__ Ob) {
  __shared__ alignas(16) __hip_bfloat16 lK[2][128 * 32];   // 8KB each
  __shared__ alignas(16) __hip_bfloat16 lV[2][32 * 128];   // 8KB each
  const int lin = blockIdx.x;           // 0..1023
  const int xcd = lin & 7;
  const int idx = lin >> 3;             // 0..127
  const int h = xcd * 2 + (idx & 1);    // 2 heads per XCD
  const int qb = 63 - (idx >> 1);       // DESCENDING: big blocks first (LPT)
  const int nt = qb + 1;                // 64-kv tiles
  const int rounds = (nt + 1) >> 1;     // 128-kv barrier rounds
  const int tid = threadIdx.x;
  const int lane = tid & 63, w = tid >> 6;
  const int g = lane >> 4, c = lane & 15;
  // staging source mapping (inverse of the LDS read permutation)
  const int krow = (tid >> 6) * 16 + (tid & 15);
  const int kcol = ((tid >> 4) & 3) * 8;
  const int vrow = ((tid >> 6) & 1) * 16 + (tid & 15);
  const int vcol = ((tid >> 7) & 1) * 32 + ((tid >> 4) & 3) * 8;
  const __hip_bfloat16* Kh = Kp + (size_t)h * TT * 32 + (size_t)krow * 32 + kcol;
  const __hip_bfloat16* Vh = Vt + (size_t)h * 32 * TT + (size_t)vrow * TT + vcol;
  const f32x4 zz = {0.f, 0.f, 0.f, 0.f};
  // pi-permuted V base byte offset within a 4KB V sub-tile (verified R13)
  const int vb0 = (g >> 1) * 256 + c * 16 + 8 * (g & 1);

  const int qrow = qb * 64 + w * 16 + c;
  const short8 qf =
      *reinterpret_cast<const short8*>(Qp + ((size_t)h * TT + qrow) * 32 + 8 * g);
  f32x4 o0 = zz, o1 = zz;
  float mst = -1e30f, lsum = 0.f;

  auto stage = [&](int r, int buf) {
#pragma unroll
    for (int sub = 0; sub < 2; ++sub) {
      const int kv = r * 128 + sub * 64;
      __builtin_amdgcn_global_load_lds(
          (const __attribute__((address_space(1))) void*)(Kh + (size_t)kv * 32),
          (__attribute__((address_space(3))) void*)(lK[buf] + sub * 2048 + tid * 8), 16, 0, 0);
      __builtin_amdgcn_global_load_lds(
          (const __attribute__((address_space(1))) void*)(Vh + kv),
          (__attribute__((address_space(3))) void*)(lV[buf] + sub * 2048 + tid * 8), 16, 0, 0);
    }
  };
  stage(0, 0);
  int cur = 0;
  for (int r = 0; r < rounds; ++r) {
    __syncthreads();  // buf[cur] staged + all waves done with buf[cur^1]
    if (r + 1 < rounds) stage(r + 1, cur ^ 1);
#pragma unroll 2
    for (int sub = 0; sub < 2; ++sub) {
      const int it = 2 * r + sub;
      if (it >= nt) break;
      const char* kb = (const char*)lK[cur] + sub * 4096;
      const char* vb = (const char*)lV[cur] + sub * 4096;
      // K fragments: addr = base + lane*16 (conflict-free)
      short8 kf[4];
#pragma unroll
      for (int ct = 0; ct < 4; ++ct)
        kf[ct] = *reinterpret_cast<const short8*>(kb + ct * 1024 + lane * 16);
      // V fragments, pi-permuted: two b64 chunks per MFMA operand
      union U8 { unsigned u[4]; short8 v8; };
      U8 aA0, aA1, aB0, aB1;
      *reinterpret_cast<uint2*>(&aA0.u[0]) = *reinterpret_cast<const uint2*>(vb + vb0);
      *reinterpret_cast<uint2*>(&aA0.u[2]) = *reinterpret_cast<const uint2*>(vb + vb0 + 512);
      *reinterpret_cast<uint2*>(&aB0.u[0]) = *reinterpret_cast<const uint2*>(vb + vb0 + 1024);
      *reinterpret_cast<uint2*>(&aB0.u[2]) = *reinterpret_cast<const uint2*>(vb + vb0 + 1536);
      *reinterpret_cast<uint2*>(&aA1.u[0]) = *reinterpret_cast<const uint2*>(vb + vb0 + 2048);
      *reinterpret_cast<uint2*>(&aA1.u[2]) = *reinterpret_cast<const uint2*>(vb + vb0 + 2560);
      *reinterpret_cast<uint2*>(&aB1.u[0]) = *reinterpret_cast<const uint2*>(vb + vb0 + 3072);
      *reinterpret_cast<uint2*>(&aB1.u[2]) = *reinterpret_cast<const uint2*>(vb + vb0 + 3584);
      f32x4 s[4];
#pragma unroll
      for (int ct = 0; ct < 4; ++ct)
        s[ct] = __builtin_amdgcn_mfma_f32_16x16x32_bf16(kf[ct], qf, zz, 0, 0, 0);  // swapped
      if (it == nt - 1) {  // diagonal tile: mask k > q
#pragma unroll
        for (int ct = 0; ct < 4; ++ct)
#pragma unroll
          for (int j = 0; j < 4; ++j)
            if (ct * 16 + g * 4 + j > w * 16 + c) s[ct][j] = -1e30f;
      }
      // in-lane max over 16 scores
      float m01 = fmaxf(fmaxf(s[0][0], s[0][1]), fmaxf(s[0][2], s[0][3]));
      float m23 = fmaxf(fmaxf(s[1][0], s[1][1]), fmaxf(s[1][2], s[1][3]));
      float m45 = fmaxf(fmaxf(s[2][0], s[2][1]), fmaxf(s[2][2], s[2][3]));
      float m67 = fmaxf(fmaxf(s[3][0], s[3][1]), fmaxf(s[3][2], s[3][3]));
      float pm_ = fmaxf(fmaxf(m01, m23), fmaxf(m45, m67));
      if (__any(pm_ > mst + 8.0f)) {  // defer-max
        float pm2 = fmaxf(pm_, __shfl_xor(pm_, 16, 64));
        pm2 = fmaxf(pm2, __shfl_xor(pm2, 32, 64));
        const float nm = fmaxf(mst, pm2);
        const float alpha = exp2f(mst - nm);
        mst = nm;
        lsum *= alpha;
#pragma unroll
        for (int j = 0; j < 4; ++j) { o0[j] *= alpha; o1[j] *= alpha; }
      }
      float ts = 0.f;
#pragma unroll
      for (int ct = 0; ct < 4; ++ct) {
#pragma unroll
        for (int j = 0; j < 4; ++j) s[ct][j] = exp2f(s[ct][j] - mst);
        ts += (s[ct][0] + s[ct][1]) + (s[ct][2] + s[ct][3]);
      }
      lsum += ts;
      // pack P to bf16 IN-LANE (pi permutation: B-frag = own values, no LDS)
      U8 pb0, pb1;
      pb0.u[0] = pk2(s[0][0], s[0][1]);
      pb0.u[1] = pk2(s[0][2], s[0][3]);
      pb0.u[2] = pk2(s[1][0], s[1][1]);
      pb0.u[3] = pk2(s[1][2], s[1][3]);
      pb1.u[0] = pk2(s[2][0], s[2][1]);
      pb1.u[1] = pk2(s[2][2], s[2][3]);
      pb1.u[2] = pk2(s[3][0], s[3][1]);
      pb1.u[3] = pk2(s[3][2], s[3][3]);
      // O^T accumulate: C col = q-row = lane c
      o0 = __builtin_amdgcn_mfma_f32_16x16x32_bf16(aA0.v8, pb0.v8, o0, 0, 0, 0);
      o0 = __builtin_amdgcn_mfma_f32_16x16x32_bf16(aA1.v8, pb1.v8, o0, 0, 0, 0);
      o1 = __builtin_amdgcn_mfma_f32_16x16x32_bf16(aB0.v8, pb0.v8, o1, 0, 0, 0);
      o1 = __builtin_amdgcn_mfma_f32_16x16x32_bf16(aB1.v8, pb1.v8, o1, 0, 0, 0);
    }
    cur ^= 1;
  }
  // final lsum reduce across g-lanes of row c; write Ob
  lsum += __shfl_xor(lsum, 16, 64);
  lsum += __shfl_xor(lsum, 32, 64);
  const float inv = 1.0f / lsum;
  __hip_bfloat16* dst = Ob + (size_t)qrow * DATTN + h * 32;
  short4v w0, w1;
#pragma unroll
  for (int j = 0; j < 4; ++j) { w0[j] = f2bf(o0[j] * inv); w1[j] = f2bf(o1[j] * inv); }
  *reinterpret_cast<short4v*>(dst + g * 4) = w0;
  *reinterpret_cast<short4v*>(dst + 16 + g * 4) = w1;
}

extern "C" void kernel_launch(void* const* d_in, const int* in_sizes, int n_in,
                              void* d_out, int out_size, void* d_ws, size_t ws_size,
                              hipStream_t stream) {
  const float* x   = (const float*)d_in[0];
  const float* qsw = (const float*)d_in[1];
  const float* ksw = (const float*)d_in[2];
  const float* qgw = (const float*)d_in[3];
  const float* kgw = (const float*)d_in[4];
  const float* vw  = (const float*)d_in[5];
  const float* ow  = (const float*)d_in[6];
  const float* ls  = (const float*)d_in[7];
  const int* posp  = (const int*)d_in[9];

  size_t off = 0;
  auto alloc = [&](size_t bytes) {
    char* p = (char*)d_ws + off;
    off += (bytes + 255) & ~(size_t)255;
    return (void*)p;
  };
  __hip_bfloat16* Xbf  = (__hip_bfloat16*)alloc((size_t)TT * DM * 2);
  __hip_bfloat16* Wcat = (__hip_bfloat16*)alloc((size_t)NPROJ * DM * 2);
  __hip_bfloat16* OW   = (__hip_bfloat16*)alloc((size_t)DM * DATTN * 2);
  __hip_bfloat16* Qp   = (__hip_bfloat16*)alloc((size_t)NH * TT * 32 * 2);
  __hip_bfloat16* Kpk  = (__hip_bfloat16*)alloc((size_t)NH * TT * 32 * 2);
  __hip_bfloat16* Vt   = (__hip_bfloat16*)alloc((size_t)NH * 32 * TT * 2);
  __hip_bfloat16* Ob   = (__hip_bfloat16*)alloc((size_t)TT * DATTN * 2);

  k_prep<<<dim3(NB_X + NB_OW + NB_WC), 256, 0, stream>>>(x, ow, qsw, ksw, qgw, kgw, vw,
                                                         Xbf, OW, Wcat);
  k_gemm_bt<1><<<dim3(TT / 64, NPROJ / 128), 256, 0, stream>>>(Xbf, Wcat, nullptr,
      TT, NPROJ, DM, Qp, Kpk, Vt, ls, posp);
  k_attn<<<dim3(1024), 256, 0, stream>>>(Qp, Kpk, Vt, Ob);
  k_gemm_bt<0><<<dim3(TT / 64, DM / 128), 256, 0, stream>>>(Ob, OW, (void*)d_out,
      TT, DM, DATTN, nullptr, nullptr, nullptr, nullptr, nullptr);
}

// Round 22
// 112.836 us; speedup vs baseline: 1.0055x; 1.0055x over previous
//
#include <hip/hip_runtime.h>
#include <hip/hip_bf16.h>

typedef __attribute__((ext_vector_type(8))) short short8;
typedef __attribute__((ext_vector_type(4))) short short4v;
typedef __attribute__((ext_vector_type(4))) float f32x4;

#define TT 4096
#define DM 1024
#define NH 16
#define NPROJ 1280   // 128 qs + 128 ks + 256 qg + 256 kg + 512 v
#define DATTN 512

static __device__ __forceinline__ short f2bf(float f) {
  __hip_bfloat16 h = __float2bfloat16(f);
  return *reinterpret_cast<short*>(&h);
}

// ---------------- fused prep: x->bf16, ow->bf16, wcat concat (one launch) ----------------
#define NB_X   (TT * DM / 4 / 256)        // 4096 blocks
#define NB_OW  (DM * DATTN / 4 / 256)     // 512 blocks
#define NB_WC  (NPROJ * DM / 4 / 256)     // 1280 blocks
__global__ __launch_bounds__(256) void k_prep(const float* __restrict__ x,
    const float* __restrict__ ow, const float* __restrict__ qs, const float* __restrict__ ks,
    const float* __restrict__ qg, const float* __restrict__ kg, const float* __restrict__ vw,
    __hip_bfloat16* __restrict__ Xbf, __hip_bfloat16* __restrict__ OW,
    __hip_bfloat16* __restrict__ Wcat) {
  const int b = blockIdx.x;
  if (b < NB_X) {
    const int i = b * 256 + threadIdx.x;
    float4 v = reinterpret_cast<const float4*>(x)[i];
    short4v o;
    o[0] = f2bf(v.x); o[1] = f2bf(v.y); o[2] = f2bf(v.z); o[3] = f2bf(v.w);
    reinterpret_cast<short4v*>(Xbf)[i] = o;
  } else if (b < NB_X + NB_OW) {
    const int i = (b - NB_X) * 256 + threadIdx.x;
    float4 v = reinterpret_cast<const float4*>(ow)[i];
    short4v o;
    o[0] = f2bf(v.x); o[1] = f2bf(v.y); o[2] = f2bf(v.z); o[3] = f2bf(v.w);
    reinterpret_cast<short4v*>(OW)[i] = o;
  } else {
    const int i = (b - NB_X - NB_OW) * 256 + threadIdx.x;
    const int idx = i * 4;
    const int row = idx >> 10;
    const int col = idx & 1023;
    const float* src;
    if (row < 128)      src = qs + (size_t)row * DM;
    else if (row < 256) src = ks + (size_t)(row - 128) * DM;
    else if (row < 512) src = qg + (size_t)(row - 256) * DM;
    else if (row < 768) src = kg + (size_t)(row - 512) * DM;
    else                src = vw + (size_t)(row - 768) * DM;
    float4 v = *reinterpret_cast<const float4*>(src + col);
    short4v o;
    o[0] = f2bf(v.x); o[1] = f2bf(v.y); o[2] = f2bf(v.z); o[3] = f2bf(v.w);
    *reinterpret_cast<short4v*>(Wcat + idx) = o;
  }
}

// ---------------- bf16 GEMM, B^T layout, BM=64 BN=128 BK=64, double-buffered ----------
// EPI=0: plain fp32 C write (out projection).
// EPI=1: fused RoPE/pack epilogue (proj GEMM), blockIdx.y selects region.
template<int EPI>
__global__ __launch_bounds__(256) void k_gemm_bt(const __hip_bfloat16* __restrict__ A,
    const __hip_bfloat16* __restrict__ B, void* __restrict__ Cv, int M, int N, int K,
    __hip_bfloat16* __restrict__ Qp, __hip_bfloat16* __restrict__ Kp,
    __hip_bfloat16* __restrict__ Vt, const float* __restrict__ ls,
    const int* __restrict__ posp) {
  __shared__ alignas(16) __hip_bfloat16 lA[2][2][64 * 32];    // [buf][kk]
  __shared__ alignas(16) __hip_bfloat16 lB[2][2][128 * 32];   // [buf][kk]
  const int tid = threadIdx.x;
  const int lane = tid & 63;
  const int wid = tid >> 6;
  const int m0 = blockIdx.x * 64, n0 = blockIdx.y * 128;
  const int wm = (wid >> 1) * 32, wn = (wid & 1) * 64;
  const int srow = tid >> 2;          // 0..63
  const int scol = (tid & 3) * 8;     // bf16 elements within a 32-col panel
  const int fr = lane & 15, fk = (lane >> 4) * 8;
  f32x4 acc[2][4];
  const f32x4 zz = {0.f, 0.f, 0.f, 0.f};
#pragma unroll
  for (int m = 0; m < 2; ++m)
#pragma unroll
    for (int n = 0; n < 4; ++n) acc[m][n] = zz;

  auto stage = [&](int kt, int buf) {
#pragma unroll
    for (int kk = 0; kk < 2; ++kk) {
      const int kcol = kt + kk * 32 + scol;
      const __hip_bfloat16* ga0 = A + (size_t)(m0 + srow) * K + kcol;
      const __hip_bfloat16* gb0 = B + (size_t)(n0 + srow) * K + kcol;
      const __hip_bfloat16* gb1 = B + (size_t)(n0 + 64 + srow) * K + kcol;
      __builtin_amdgcn_global_load_lds((const __attribute__((address_space(1))) void*)ga0,
          (__attribute__((address_space(3))) void*)(lA[buf][kk] + srow * 32 + scol), 16, 0, 0);
      __builtin_amdgcn_global_load_lds((const __attribute__((address_space(1))) void*)gb0,
          (__attribute__((address_space(3))) void*)(lB[buf][kk] + srow * 32 + scol), 16, 0, 0);
      __builtin_amdgcn_global_load_lds((const __attribute__((address_space(1))) void*)gb1,
          (__attribute__((address_space(3))) void*)(lB[buf][kk] + (64 + srow) * 32 + scol), 16, 0, 0);
    }
  };
  stage(0, 0);
  int buf = 0;
  for (int kt = 0; kt < K; kt += 64) {
    __syncthreads();   // staging of buf complete; prev reads of buf^1 done
    if (kt + 64 < K) stage(kt + 64, buf ^ 1);
#pragma unroll
    for (int kk = 0; kk < 2; ++kk) {
      short8 af[2], bfr[4];
#pragma unroll
      for (int m = 0; m < 2; ++m)
        af[m] = *reinterpret_cast<const short8*>(lA[buf][kk] + (wm + m * 16 + fr) * 32 + fk);
#pragma unroll
      for (int n = 0; n < 4; ++n)
        bfr[n] = *reinterpret_cast<const short8*>(lB[buf][kk] + (wn + n * 16 + fr) * 32 + fk);
#pragma unroll
      for (int m = 0; m < 2; ++m)
#pragma unroll
        for (int n = 0; n < 4; ++n)
          acc[m][n] = __builtin_amdgcn_mfma_f32_16x16x32_bf16(af[m], bfr[n], acc[m][n], 0, 0, 0);
    }
    buf ^= 1;
  }
  const int cr = (lane >> 4) * 4, cc = lane & 15;
  if (EPI == 0) {
#pragma unroll
    for (int m = 0; m < 2; ++m)
#pragma unroll
      for (int n = 0; n < 4; ++n)
#pragma unroll
        for (int j = 0; j < 4; ++j) {
          const int row = m0 + wm + m * 16 + cr + j;
          const int col = n0 + wn + n * 16 + cc;
          ((float*)Cv)[(size_t)row * N + col] = acc[m][n][j];
        }
    return;
  }
  // ---- EPI=1: fused RoPE/pack epilogue ----
  const int y = blockIdx.y;
  const float QSC = 0.20412414523193154f * 1.4426950408889634f;  // 1/sqrt(24)*log2(e)
  if (y < 2) {
    __hip_bfloat16* P = (y == 0) ? Qp : Kp;
    const __hip_bfloat16 zb = __float2bfloat16(0.f);
#pragma unroll
    for (int n = 0; n < 4; ++n) {
      const int cl = wn + n * 16 + cc;        // 0..127
      const int h = cl >> 3, d = cl & 7;
      const float sc = (y == 0) ? QSC * __expf(ls[h]) : 1.0f;
#pragma unroll
      for (int m = 0; m < 2; ++m)
#pragma unroll
        for (int j = 0; j < 4; ++j) {
          const int row = m0 + wm + m * 16 + cr + j;
          __hip_bfloat16* base = P + ((size_t)h * TT + row) * 32;
          base[d] = __float2bfloat16(acc[m][n][j] * sc);
          base[24 + d] = zb;
        }
    }
  } else if (y < 6) {
    const int isQ = (y < 4);
    __hip_bfloat16* P = isQ ? Qp : Kp;
    const int segbase = isQ ? 256 : 512;
    const float invf[8] = {1.0f, 0.31622776601683794f, 0.1f, 0.031622776601683794f,
                           0.01f, 0.0031622776601683794f, 0.001f, 0.00031622776601683794f};
    const float fr_ = invf[cc & 7];
    const float pofs = (float)posp[0];
    const int lo = (cc < 8);
    const int d = 8 + cc;                     // 8..24
#pragma unroll
    for (int n = 0; n < 4; ++n) {
      const int h = (y * 128 + wn + n * 16 - segbase) >> 4;
      const float sc = isQ ? QSC * __expf(ls[h]) : 1.0f;
#pragma unroll
      for (int m = 0; m < 2; ++m)
#pragma unroll
        for (int j = 0; j < 4; ++j) {
          const int row = m0 + wm + m * 16 + cr + j;
          const float own = acc[m][n][j];
          const float oth = __shfl_xor(own, 8, 64);
          float ss, cs;
          __sincosf((row + pofs) * fr_, &ss, &cs);
          const float out = lo ? (own * cs - oth * ss) : (oth * ss + own * cs);
          P[((size_t)h * TT + row) * 32 + d] = __float2bfloat16(out * sc);
        }
    }
  } else {
#pragma unroll
    for (int n = 0; n < 4; ++n) {
      const int local = y * 128 + wn + n * 16 - 768 + cc;   // 0..511
      const int h = local >> 5, d = local & 31;
#pragma unroll
      for (int m = 0; m < 2; ++m) {
        short4v pk;
#pragma unroll
        for (int j = 0; j < 4; ++j) pk[j] = f2bf(acc[m][n][j]);
        const int row0 = m0 + wm + m * 16 + cr;   // multiple of 4
        *reinterpret_cast<short4v*>(Vt + ((size_t)h * 32 + d) * TT + row0) = pk;
      }
    }
  }
}

// ---------------- causal flash attention (R11: LDS K/V, LPT, 4 blocks/CU) -------------
__global__ __launch_bounds__(256) void k_attn(const __hip_bfloat16* __restrict__ Qp,
    const __hip_bfloat16* __restrict__ Kp, const __hip_bfloat16* __restrict__ Vt,
    __hip_bfloat16* __restrict__ Ob) {
  __shared__ alignas(16) __hip_bfloat16 lK[2][64 * 32];   // 4KB each
  __shared__ alignas(16) __hip_bfloat16 lV[2][32 * 64];   // 4KB each
  __shared__ alignas(16) __hip_bfloat16 Plds[4][16][72];
  const int lin = blockIdx.x;           // 0..1023
  const int xcd = lin & 7;
  const int idx = lin >> 3;             // 0..127
  const int h = xcd * 2 + (idx & 1);    // 2 heads per XCD
  const int qb = 63 - (idx >> 1);       // DESCENDING: big blocks first (LPT)
  const int nt = qb + 1;
  const int tid = threadIdx.x;
  const int lane = tid & 63, w = tid >> 6;
  const int g = lane >> 4, c = lane & 15;
  // staging source mapping (inverse of the LDS read permutation)
  const int krow = (tid >> 6) * 16 + (tid & 15);
  const int kcol = ((tid >> 4) & 3) * 8;
  const int vrow = ((tid >> 6) & 1) * 16 + (tid & 15);
  const int vcol = ((tid >> 7) & 1) * 32 + ((tid >> 4) & 3) * 8;
  const __hip_bfloat16* Kh = Kp + (size_t)h * TT * 32 + (size_t)krow * 32 + kcol;
  const __hip_bfloat16* Vh = Vt + (size_t)h * 32 * TT + (size_t)vrow * TT + vcol;
  const f32x4 zz = {0.f, 0.f, 0.f, 0.f};

  const int qrow = qb * 64 + w * 16 + c;
  const short8 qf =
      *reinterpret_cast<const short8*>(Qp + ((size_t)h * TT + qrow) * 32 + 8 * g);
  f32x4 o0 = zz, o1 = zz;
  float mst = -1e30f, lsum = 0.f;
  int cur = 0;
  __builtin_amdgcn_global_load_lds(
      (const __attribute__((address_space(1))) void*)Kh,
      (__attribute__((address_space(3))) void*)(lK[0] + tid * 8), 16, 0, 0);
  __builtin_amdgcn_global_load_lds(
      (const __attribute__((address_space(1))) void*)Vh,
      (__attribute__((address_space(3))) void*)(lV[0] + tid * 8), 16, 0, 0);

  for (int it = 0; it < nt; ++it) {
    __syncthreads();  // buf[cur] staged + all waves done with buf[cur^1]
    if (it + 1 < nt) {
      const int kv1 = (it + 1) * 64;
      __builtin_amdgcn_global_load_lds(
          (const __attribute__((address_space(1))) void*)(Kh + (size_t)kv1 * 32),
          (__attribute__((address_space(3))) void*)(lK[cur ^ 1] + tid * 8), 16, 0, 0);
      __builtin_amdgcn_global_load_lds(
          (const __attribute__((address_space(1))) void*)(Vh + kv1),
          (__attribute__((address_space(3))) void*)(lV[cur ^ 1] + tid * 8), 16, 0, 0);
    }
    // K fragments: addr = base + lane*16 (conflict-free)
    const char* kb = (const char*)lK[cur];
    short8 kf[4];
#pragma unroll
    for (int ct = 0; ct < 4; ++ct)
      kf[ct] = *reinterpret_cast<const short8*>(kb + ct * 1024 + lane * 16);
    // V fragments: addr = base + lane*16 (conflict-free)
    const char* vb = (const char*)lV[cur];
    const short8 v00 = *reinterpret_cast<const short8*>(vb + lane * 16);
    const short8 v10 = *reinterpret_cast<const short8*>(vb + 1024 + lane * 16);
    const short8 v01 = *reinterpret_cast<const short8*>(vb + 2048 + lane * 16);
    const short8 v11 = *reinterpret_cast<const short8*>(vb + 3072 + lane * 16);
    f32x4 s[4];
#pragma unroll
    for (int ct = 0; ct < 4; ++ct)
      s[ct] = __builtin_amdgcn_mfma_f32_16x16x32_bf16(kf[ct], qf, zz, 0, 0, 0);  // swapped
    if (it == nt - 1) {  // diagonal tile: mask k > q
#pragma unroll
      for (int ct = 0; ct < 4; ++ct)
#pragma unroll
        for (int j = 0; j < 4; ++j)
          if (ct * 16 + g * 4 + j > w * 16 + c) s[ct][j] = -1e30f;
    }
    // in-lane max over 16 scores
    float m01 = fmaxf(fmaxf(s[0][0], s[0][1]), fmaxf(s[0][2], s[0][3]));
    float m23 = fmaxf(fmaxf(s[1][0], s[1][1]), fmaxf(s[1][2], s[1][3]));
    float m45 = fmaxf(fmaxf(s[2][0], s[2][1]), fmaxf(s[2][2], s[2][3]));
    float m67 = fmaxf(fmaxf(s[3][0], s[3][1]), fmaxf(s[3][2], s[3][3]));
    float pm_ = fmaxf(fmaxf(m01, m23), fmaxf(m45, m67));
    if (__any(pm_ > mst + 8.0f)) {  // defer-max
      float pm2 = fmaxf(pm_, __shfl_xor(pm_, 16, 64));
      pm2 = fmaxf(pm2, __shfl_xor(pm2, 32, 64));
      const float nm = fmaxf(mst, pm2);
      const float alpha = exp2f(mst - nm);
      mst = nm;
      lsum *= alpha;
#pragma unroll
      for (int j = 0; j < 4; ++j) { o0[j] *= alpha; o1[j] *= alpha; }
    }
    float ts = 0.f;
#pragma unroll
    for (int ct = 0; ct < 4; ++ct) {
#pragma unroll
      for (int j = 0; j < 4; ++j) s[ct][j] = exp2f(s[ct][j] - mst);
      ts += (s[ct][0] + s[ct][1]) + (s[ct][2] + s[ct][3]);
    }
    lsum += ts;
    // P -> LDS (packed bf16 pairs), per-wave private slice (2-way max: free)
#pragma unroll
    for (int ct = 0; ct < 4; ++ct) {
      float2 p01; p01.x = s[ct][0]; p01.y = s[ct][1];
      float2 p23; p23.x = s[ct][2]; p23.y = s[ct][3];
      __hip_bfloat162 b01 = __float22bfloat162_rn(p01);
      __hip_bfloat162 b23 = __float22bfloat162_rn(p23);
      *reinterpret_cast<__hip_bfloat162*>(&Plds[w][c][ct * 16 + g * 4]) = b01;
      *reinterpret_cast<__hip_bfloat162*>(&Plds[w][c][ct * 16 + g * 4 + 2]) = b23;
    }
    const short8 pf0 = *reinterpret_cast<const short8*>(&Plds[w][c][8 * g]);
    const short8 pf1 = *reinterpret_cast<const short8*>(&Plds[w][c][32 + 8 * g]);
    // O^T: C col = q-row = lane c
    o0 = __builtin_amdgcn_mfma_f32_16x16x32_bf16(v00, pf0, o0, 0, 0, 0);
    o0 = __builtin_amdgcn_mfma_f32_16x16x32_bf16(v01, pf1, o0, 0, 0, 0);
    o1 = __builtin_amdgcn_mfma_f32_16x16x32_bf16(v10, pf0, o1, 0, 0, 0);
    o1 = __builtin_amdgcn_mfma_f32_16x16x32_bf16(v11, pf1, o1, 0, 0, 0);
    cur ^= 1;
  }
  // final lsum reduce across g-lanes of row c; write Ob
  lsum += __shfl_xor(lsum, 16, 64);
  lsum += __shfl_xor(lsum, 32, 64);
  const float inv = 1.0f / lsum;
  __hip_bfloat16* dst = Ob + (size_t)qrow * DATTN + h * 32;
  short4v w0, w1;
#pragma unroll
  for (int j = 0; j < 4; ++j) { w0[j] = f2bf(o0[j] * inv); w1[j] = f2bf(o1[j] * inv); }
  *reinterpret_cast<short4v*>(dst + g * 4) = w0;
  *reinterpret_cast<short4v*>(dst + 16 + g * 4) = w1;
}

extern "C" void kernel_launch(void* const* d_in, const int* in_sizes, int n_in,
                              void* d_out, int out_size, void* d_ws, size_t ws_size,
                              hipStream_t stream) {
  const float* x   = (const float*)d_in[0];
  const float* qsw = (const float*)d_in[1];
  const float* ksw = (const float*)d_in[2];
  const float* qgw = (const float*)d_in[3];
  const float* kgw = (const float*)d_in[4];
  const float* vw  = (const float*)d_in[5];
  const float* ow  = (const float*)d_in[6];
  const float* ls  = (const float*)d_in[7];
  const int* posp  = (const int*)d_in[9];

  size_t off = 0;
  auto alloc = [&](size_t bytes) {
    char* p = (char*)d_ws + off;
    off += (bytes + 255) & ~(size_t)255;
    return (void*)p;
  };
  __hip_bfloat16* Xbf  = (__hip_bfloat16*)alloc((size_t)TT * DM * 2);
  __hip_bfloat16* Wcat = (__hip_bfloat16*)alloc((size_t)NPROJ * DM * 2);
  __hip_bfloat16* OW   = (__hip_bfloat16*)alloc((size_t)DM * DATTN * 2);
  __hip_bfloat16* Qp   = (__hip_bfloat16*)alloc((size_t)NH * TT * 32 * 2);
  __hip_bfloat16* Kpk  = (__hip_bfloat16*)alloc((size_t)NH * TT * 32 * 2);
  __hip_bfloat16* Vt   = (__hip_bfloat16*)alloc((size_t)NH * 32 * TT * 2);
  __hip_bfloat16* Ob   = (__hip_bfloat16*)alloc((size_t)TT * DATTN * 2);

  k_prep<<<dim3(NB_X + NB_OW + NB_WC), 256, 0, stream>>>(x, ow, qsw, ksw, qgw, kgw, vw,
                                                         Xbf, OW, Wcat);
  k_gemm_bt<1><<<dim3(TT / 64, NPROJ / 128), 256, 0, stream>>>(Xbf, Wcat, nullptr,
      TT, NPROJ, DM, Qp, Kpk, Vt, ls, posp);
  k_attn<<<dim3(1024), 256, 0, stream>>>(Qp, Kpk, Vt, Ob);
  k_gemm_bt<0><<<dim3(TT / 64, DM / 128), 256, 0, stream>>>(Ob, OW, (void*)d_out,
      TT, DM, DATTN, nullptr, nullptr, nullptr, nullptr, nullptr);
}